// Round 1
// baseline (451.769 us; speedup 1.0000x reference)
//
#include <hip/hip_runtime.h>

typedef unsigned short us;
typedef short s16x8 __attribute__((ext_vector_type(8)));
typedef float f32x4 __attribute__((ext_vector_type(4)));

__device__ __forceinline__ us f2bf(float f) {
  union { float f; unsigned u; } v; v.f = f;
  unsigned u = v.u;
  u += 0x7fffu + ((u >> 16) & 1u);   // RNE
  return (us)(u >> 16);
}

__device__ __forceinline__ s16x8 ld8(const us* p) { return *(const s16x8*)p; }

#define MFMA(a, b, c) __builtin_amdgcn_mfma_f32_16x16x32_bf16(a, b, c, 0, 0, 0)

__device__ __forceinline__ float qsum(float v) {
  v += __shfl_xor(v, 1, 64); v += __shfl_xor(v, 2, 64);
  v += __shfl_xor(v, 4, 64); v += __shfl_xor(v, 8, 64);
  return v;
}
__device__ __forceinline__ float qmax(float v) {
  v = fmaxf(v, __shfl_xor(v, 1, 64)); v = fmaxf(v, __shfl_xor(v, 2, 64));
  v = fmaxf(v, __shfl_xor(v, 4, 64)); v = fmaxf(v, __shfl_xor(v, 8, 64));
  return v;
}
__device__ __forceinline__ int cls3(int v) { return v < 120 ? 0 : (v < 124 ? 1 : 2); }

// ---------- K0: weight swizzle. src (N,K) row-major fp32 (i.e. W so out = x @ W^T).
// dst[((k>>3)*N + n)*8 + (k&7)] = bf16(W[n][k])  -> B-fragment = one 16B load.
__global__ void swz_kernel(const float* __restrict__ src, us* __restrict__ dst, int N, int K) {
  int id = blockIdx.x * 256 + threadIdx.x;
  if (id >= N * K) return;
  int n = id % N, k = id / N;
  dst[(((k >> 3) * N + n) << 3) + (k & 7)] = f2bf(src[n * K + k]);
}

// ---------- K1: per (window, head): gather+roll -> QKV GEMM -> attention -> attn_out bf16
__global__ __launch_bounds__(256) void attn_kernel(
    const float* __restrict__ x_v, const us* __restrict__ qkvw,
    const float* __restrict__ qkv_b, const float* __restrict__ rpb_table,
    us* __restrict__ attn_out) {
  __shared__ __align__(16) unsigned char smem[64000];
  us* XW = (us*)smem;                   // [128][136] x window (freed after QKV)
  us* Qb = (us*)(smem + 34816);         // [128][40]
  us* Kb = (us*)(smem + 45056);         // [128][40]
  us* Vt = (us*)(smem + 55296);         // [32][136]  (V transposed)
  float* rpbL = (float*)(smem + 17408); // [64][64]   (in XW area, post-GEMM)

  int bid = blockIdx.x;
  int w = bid >> 2, h = bid & 3;
  int b = w >> 8, wi = w & 255, wh = wi >> 4, ww = wi & 15;
  int tid = threadIdx.x;

  { // gather: rolled(p) = orig((p+4)&127)
    int token = tid >> 1, half = tid & 1;
    int t = token >> 6, n = token & 63, r = n >> 3, c = n & 7;
    int hs = (wh * 8 + r + 4) & 127, wsc = (ww * 8 + c + 4) & 127;
    const float* src = x_v + (size_t)((b * 2 + t) * 16384 + hs * 128 + wsc) * 128 + half * 64;
    us* dst = XW + token * 136 + half * 64;
#pragma unroll
    for (int i = 0; i < 8; ++i) {
      float4 f0 = ((const float4*)src)[2 * i];
      float4 f1 = ((const float4*)src)[2 * i + 1];
      s16x8 v;
      v[0] = (short)f2bf(f0.x); v[1] = (short)f2bf(f0.y);
      v[2] = (short)f2bf(f0.z); v[3] = (short)f2bf(f0.w);
      v[4] = (short)f2bf(f1.x); v[5] = (short)f2bf(f1.y);
      v[6] = (short)f2bf(f1.z); v[7] = (short)f2bf(f1.w);
      *(s16x8*)(dst + i * 8) = v;
    }
  }
  __syncthreads();

  int lane = tid & 63, wv = tid >> 6, quad = lane >> 4, c16 = lane & 15;

  // ---- QKV GEMM: rows [wv*32,+32), cols Q|K|V head slice (96)
  f32x4 qacc[2][6];
#pragma unroll
  for (int mi = 0; mi < 2; ++mi)
#pragma unroll
    for (int ni = 0; ni < 6; ++ni) qacc[mi][ni] = (f32x4){0.f, 0.f, 0.f, 0.f};

#pragma unroll
  for (int ks = 0; ks < 4; ++ks) {
    int k0 = ks * 32;
    s16x8 af[2];
#pragma unroll
    for (int mi = 0; mi < 2; ++mi)
      af[mi] = ld8(XW + (wv * 32 + mi * 16 + c16) * 136 + k0 + quad * 8);
#pragma unroll
    for (int ni = 0; ni < 6; ++ni) {
      int ng = (ni >> 1) * 128 + h * 32 + (ni & 1) * 16 + c16;
      s16x8 bf = ld8(qkvw + ((((k0 >> 3) + quad) * 384 + ng) << 3));
#pragma unroll
      for (int mi = 0; mi < 2; ++mi) qacc[mi][ni] = MFMA(af[mi], bf, qacc[mi][ni]);
    }
  }
  // write Q (scaled), K, V^T to LDS
#pragma unroll
  for (int mi = 0; mi < 2; ++mi)
#pragma unroll
    for (int ni = 0; ni < 6; ++ni) {
      int part = ni >> 1;
      int colh = (ni & 1) * 16 + c16;
      float bias = qkv_b[part * 128 + h * 32 + colh];
#pragma unroll
      for (int r = 0; r < 4; ++r) {
        int tok = wv * 32 + mi * 16 + quad * 4 + r;
        float v = qacc[mi][ni][r] + bias;
        if (part == 0) Qb[tok * 40 + colh] = f2bf(v * 0.17677669529663687f);
        else if (part == 1) Kb[tok * 40 + colh] = f2bf(v);
        else Vt[colh * 136 + tok] = f2bf(v);
      }
    }
  __syncthreads();  // QKV ready; XW area free

  // stage rpb[n1][n2] for this head
  for (int e = tid; e < 4096; e += 256) {
    int n1 = e >> 6, n2 = e & 63;
    int idx = ((n1 >> 3) - (n2 >> 3) + 7) * 15 + ((n1 & 7) - (n2 & 7) + 7);
    rpbL[e] = rpb_table[idx * 4 + h];
  }
  __syncthreads();

  us* Pw = (us*)(smem + wv * 4352);  // per-wave [16][136] P scratch (in XW area)

#pragma unroll
  for (int qc = 0; qc < 2; ++qc) {
    int q0 = wv * 32 + qc * 16;
    s16x8 aq = ld8(Qb + (q0 + c16) * 40 + quad * 8);
    f32x4 sacc[8];
#pragma unroll
    for (int nj = 0; nj < 8; ++nj) {
      s16x8 bk = ld8(Kb + (nj * 16 + c16) * 40 + quad * 8);
      sacc[nj] = MFMA(aq, bk, ((f32x4){0.f, 0.f, 0.f, 0.f}));
    }
    // bias + mask + softmax (rows live in quad: row = q0 + quad*4 + r)
    float mx[4] = {-1e30f, -1e30f, -1e30f, -1e30f};
#pragma unroll
    for (int nj = 0; nj < 8; ++nj) {
      int kt = nj * 16 + c16, nk = kt & 63;
      int r2 = nk >> 3, c2 = nk & 7;
      int ck = cls3(wh * 8 + r2) * 3 + cls3(ww * 8 + c2);
#pragma unroll
      for (int r = 0; r < 4; ++r) {
        int qt = q0 + quad * 4 + r, nq = qt & 63;
        int r1 = nq >> 3, c1 = nq & 7;
        int cq = cls3(wh * 8 + r1) * 3 + cls3(ww * 8 + c1);
        float s = sacc[nj][r] + rpbL[nq * 64 + nk] + (cq != ck ? -100.f : 0.f);
        sacc[nj][r] = s;
        mx[r] = fmaxf(mx[r], s);
      }
    }
#pragma unroll
    for (int r = 0; r < 4; ++r) mx[r] = qmax(mx[r]);
    float sm[4] = {0.f, 0.f, 0.f, 0.f};
#pragma unroll
    for (int nj = 0; nj < 8; ++nj)
#pragma unroll
      for (int r = 0; r < 4; ++r) {
        float p = __expf(sacc[nj][r] - mx[r]);
        sacc[nj][r] = p;
        sm[r] += p;
      }
    float inv[4];
#pragma unroll
    for (int r = 0; r < 4; ++r) inv[r] = 1.f / qsum(sm[r]);
    // P -> LDS (A-operand layout round-trip, m120 pattern)
#pragma unroll
    for (int nj = 0; nj < 8; ++nj)
#pragma unroll
      for (int r = 0; r < 4; ++r)
        Pw[(quad * 4 + r) * 136 + nj * 16 + c16] = f2bf(sacc[nj][r] * inv[r]);
    // PV
    f32x4 oacc[2];
    oacc[0] = (f32x4){0.f, 0.f, 0.f, 0.f};
    oacc[1] = (f32x4){0.f, 0.f, 0.f, 0.f};
#pragma unroll
    for (int ks = 0; ks < 4; ++ks) {
      int k0 = ks * 32;
      s16x8 ap = ld8(Pw + c16 * 136 + k0 + quad * 8);
#pragma unroll
      for (int nt = 0; nt < 2; ++nt) {
        s16x8 bv = ld8(Vt + (nt * 16 + c16) * 136 + k0 + quad * 8);
        oacc[nt] = MFMA(ap, bv, oacc[nt]);
      }
    }
#pragma unroll
    for (int nt = 0; nt < 2; ++nt)
#pragma unroll
      for (int r = 0; r < 4; ++r) {
        int tok = q0 + quad * 4 + r;
        attn_out[((size_t)w * 128 + tok) * 128 + h * 32 + nt * 16 + c16] =
            f2bf(oacc[nt][r]);
      }
  }
}

// ---------- K2: proj + window-reverse + roll-back + shortcut -> x_resid fp32
__global__ __launch_bounds__(256) void proj_kernel(
    const us* __restrict__ attn_ws, const us* __restrict__ projw,
    const float* __restrict__ proj_b, const float* __restrict__ x_v,
    float* __restrict__ x_resid) {
  __shared__ __align__(16) us A[128 * 136];
  int w = blockIdx.x;
  int b = w >> 8, wi = w & 255, wh = wi >> 4, ww = wi & 15;
  int tid = threadIdx.x;
  {
    int token = tid >> 1, half = tid & 1;
    const us* src = attn_ws + ((size_t)w * 128 + token) * 128 + half * 64;
    us* dst = A + token * 136 + half * 64;
#pragma unroll
    for (int i = 0; i < 8; ++i) *(s16x8*)(dst + i * 8) = ld8(src + i * 8);
  }
  __syncthreads();

  int lane = tid & 63, wv = tid >> 6, quad = lane >> 4, c16 = lane & 15;
  int wr = (wv >> 1) * 64, wc = (wv & 1) * 64;
  f32x4 acc[4][4];
#pragma unroll
  for (int mi = 0; mi < 4; ++mi)
#pragma unroll
    for (int ni = 0; ni < 4; ++ni) acc[mi][ni] = (f32x4){0.f, 0.f, 0.f, 0.f};

#pragma unroll
  for (int ks = 0; ks < 4; ++ks) {
    int k0 = ks * 32;
    s16x8 af[4];
#pragma unroll
    for (int mi = 0; mi < 4; ++mi)
      af[mi] = ld8(A + (wr + mi * 16 + c16) * 136 + k0 + quad * 8);
#pragma unroll
    for (int ni = 0; ni < 4; ++ni) {
      s16x8 bf = ld8(projw + ((((k0 >> 3) + quad) * 128 + wc + ni * 16 + c16) << 3));
#pragma unroll
      for (int mi = 0; mi < 4; ++mi) acc[mi][ni] = MFMA(af[mi], bf, acc[mi][ni]);
    }
  }
#pragma unroll
  for (int mi = 0; mi < 4; ++mi)
#pragma unroll
    for (int r = 0; r < 4; ++r) {
      int m = wr + mi * 16 + quad * 4 + r;
      int t = m >> 6, n = m & 63, rr = n >> 3, cc = n & 7;
      int hf = (wh * 8 + rr + 4) & 127, wf = (ww * 8 + cc + 4) & 127;
      size_t grow = (size_t)((b * 2 + t) * 16384 + hf * 128 + wf) * 128;
#pragma unroll
      for (int ni = 0; ni < 4; ++ni) {
        int col = wc + ni * 16 + c16;
        x_resid[grow + col] = acc[mi][ni][r] + proj_b[col] + x_v[grow + col];
      }
    }
}

// ---------- K3: LN(norm2) -> fc1+GELU -> fc2 -> x += h  (in-place on x_resid)
__global__ __launch_bounds__(256) void mlp_kernel(
    float* __restrict__ x_resid, const us* __restrict__ fc1w,
    const us* __restrict__ fc2w, const float* __restrict__ fc1_b,
    const float* __restrict__ fc2_b, const float* __restrict__ n2w,
    const float* __restrict__ n2b) {
  __shared__ __align__(16) unsigned char smem[53248];
  us* A = (us*)smem;             // [128][136] LN'd x, bf16
  us* Hs = (us*)(smem + 34816);  // [128][72]  gelu chunk, bf16
  int tb = blockIdx.x * 128;
  int tid = threadIdx.x;
  int lane = tid & 63, wv = tid >> 6, quad = lane >> 4, c16 = lane & 15;

  // LN phase: one token per quad-group per iteration
#pragma unroll
  for (int it = 0; it < 8; ++it) {
    int tl = it * 16 + wv * 4 + quad;
    const float* xr = x_resid + (size_t)(tb + tl) * 128 + c16 * 8;
    float4 a0 = ((const float4*)xr)[0];
    float4 a1 = ((const float4*)xr)[1];
    float vals[8] = {a0.x, a0.y, a0.z, a0.w, a1.x, a1.y, a1.z, a1.w};
    float s = 0.f, sq = 0.f;
#pragma unroll
    for (int j = 0; j < 8; ++j) { s += vals[j]; sq += vals[j] * vals[j]; }
    s = qsum(s); sq = qsum(sq);
    float mean = s * 0.0078125f;
    float var = sq * 0.0078125f - mean * mean;
    float rstd = rsqrtf(var + 1e-5f);
    s16x8 v;
#pragma unroll
    for (int j = 0; j < 8; ++j) {
      int cidx = c16 * 8 + j;
      v[j] = (short)f2bf((vals[j] - mean) * rstd * n2w[cidx] + n2b[cidx]);
    }
    *(s16x8*)(A + tl * 136 + c16 * 8) = v;
  }
  __syncthreads();

  int wr = (wv >> 1) * 64, wc = (wv & 1) * 64;
  f32x4 oacc[4][4];
#pragma unroll
  for (int mi = 0; mi < 4; ++mi)
#pragma unroll
    for (int ni = 0; ni < 4; ++ni) oacc[mi][ni] = (f32x4){0.f, 0.f, 0.f, 0.f};

  for (int cc = 0; cc < 8; ++cc) {
    // fc1 chunk: out 128 x 64, rows [wv*32,+32) per wave
    f32x4 facc[2][4];
#pragma unroll
    for (int mi = 0; mi < 2; ++mi)
#pragma unroll
      for (int ni = 0; ni < 4; ++ni) facc[mi][ni] = (f32x4){0.f, 0.f, 0.f, 0.f};
#pragma unroll
    for (int ks = 0; ks < 4; ++ks) {
      int k0 = ks * 32;
      s16x8 af[2];
#pragma unroll
      for (int mi = 0; mi < 2; ++mi)
        af[mi] = ld8(A + (wv * 32 + mi * 16 + c16) * 136 + k0 + quad * 8);
#pragma unroll
      for (int ni = 0; ni < 4; ++ni) {
        int n = cc * 64 + ni * 16 + c16;
        s16x8 bf = ld8(fc1w + ((((k0 >> 3) + quad) * 512 + n) << 3));
#pragma unroll
        for (int mi = 0; mi < 2; ++mi) facc[mi][ni] = MFMA(af[mi], bf, facc[mi][ni]);
      }
    }
#pragma unroll
    for (int mi = 0; mi < 2; ++mi)
#pragma unroll
      for (int ni = 0; ni < 4; ++ni) {
        float bb = fc1_b[cc * 64 + ni * 16 + c16];
#pragma unroll
        for (int r = 0; r < 4; ++r) {
          float u = facc[mi][ni][r] + bb;
          float g = 0.5f * u * (1.f + erff(u * 0.70710678118654752f));
          Hs[(wv * 32 + mi * 16 + quad * 4 + r) * 72 + ni * 16 + c16] = f2bf(g);
        }
      }
    __syncthreads();
    // fc2 accumulate: K-chunk 64
#pragma unroll
    for (int ks = 0; ks < 2; ++ks) {
      int k0 = ks * 32;
      s16x8 af[4];
#pragma unroll
      for (int mi = 0; mi < 4; ++mi)
        af[mi] = ld8(Hs + (wr + mi * 16 + c16) * 72 + k0 + quad * 8);
#pragma unroll
      for (int ni = 0; ni < 4; ++ni) {
        s16x8 bf = ld8(fc2w + (((((cc * 64 + k0) >> 3) + quad) * 128 + wc + ni * 16 + c16) << 3));
#pragma unroll
        for (int mi = 0; mi < 4; ++mi) oacc[mi][ni] = MFMA(af[mi], bf, oacc[mi][ni]);
      }
    }
    __syncthreads();
  }
  // epilogue: x_resid = x + h
#pragma unroll
  for (int mi = 0; mi < 4; ++mi)
#pragma unroll
    for (int r = 0; r < 4; ++r) {
      int m = wr + mi * 16 + quad * 4 + r;
      size_t row = (size_t)(tb + m) * 128;
#pragma unroll
      for (int ni = 0; ni < 4; ++ni) {
        int col = wc + ni * 16 + c16;
        x_resid[row + col] = oacc[mi][ni][r] + fc2_b[col] + x_resid[row + col];
      }
    }
}

// ---------- K4: final LN(norm1) -> out
__global__ __launch_bounds__(256) void ln_kernel(
    const float* __restrict__ xh, const float* __restrict__ n1w,
    const float* __restrict__ n1b, float* __restrict__ out) {
  int tid = threadIdx.x;
  int lane = tid & 63, wv = tid >> 6, quad = lane >> 4, c16 = lane & 15;
  int tb = blockIdx.x * 64;
#pragma unroll
  for (int it = 0; it < 4; ++it) {
    int token = tb + it * 16 + wv * 4 + quad;
    const float* xr = xh + (size_t)token * 128 + c16 * 8;
    float4 a0 = ((const float4*)xr)[0];
    float4 a1 = ((const float4*)xr)[1];
    float vals[8] = {a0.x, a0.y, a0.z, a0.w, a1.x, a1.y, a1.z, a1.w};
    float s = 0.f, sq = 0.f;
#pragma unroll
    for (int j = 0; j < 8; ++j) { s += vals[j]; sq += vals[j] * vals[j]; }
    s = qsum(s); sq = qsum(sq);
    float mean = s * 0.0078125f;
    float var = sq * 0.0078125f - mean * mean;
    float rstd = rsqrtf(var + 1e-5f);
    float4 o0, o1;
    float ov[8];
#pragma unroll
    for (int j = 0; j < 8; ++j) {
      int cidx = c16 * 8 + j;
      ov[j] = (vals[j] - mean) * rstd * n1w[cidx] + n1b[cidx];
    }
    o0.x = ov[0]; o0.y = ov[1]; o0.z = ov[2]; o0.w = ov[3];
    o1.x = ov[4]; o1.y = ov[5]; o1.z = ov[6]; o1.w = ov[7];
    float* op = out + (size_t)token * 128 + c16 * 8;
    ((float4*)op)[0] = o0;
    ((float4*)op)[1] = o1;
  }
}

extern "C" void kernel_launch(void* const* d_in, const int* in_sizes, int n_in,
                              void* d_out, int out_size, void* d_ws, size_t ws_size,
                              hipStream_t stream) {
  const float* x_v   = (const float*)d_in[0];
  const float* qkv_w = (const float*)d_in[1];
  const float* qkv_b = (const float*)d_in[2];
  const float* proj_w = (const float*)d_in[3];
  const float* proj_b = (const float*)d_in[4];
  const float* rpb_t = (const float*)d_in[5];
  const float* n1w = (const float*)d_in[6];
  const float* n1b = (const float*)d_in[7];
  const float* n2w = (const float*)d_in[8];
  const float* n2b = (const float*)d_in[9];
  const float* fc1_w = (const float*)d_in[10];
  const float* fc1_b = (const float*)d_in[11];
  const float* fc2_w = (const float*)d_in[12];
  const float* fc2_b = (const float*)d_in[13];

  char* ws = (char*)d_ws;
  us* qkvw   = (us*)(ws + 0);          //  98304 B
  us* projw  = (us*)(ws + 98304);      //  32768 B
  us* fc1w   = (us*)(ws + 131072);     // 131072 B
  us* fc2w   = (us*)(ws + 262144);     // 131072 B
  us* attn_ws = (us*)(ws + 393216);    // 32 MiB bf16
  float* x_resid = (float*)(ws + 33947648);  // 64 MiB fp32

  swz_kernel<<<192, 256, 0, stream>>>(qkv_w, qkvw, 384, 128);
  swz_kernel<<<64, 256, 0, stream>>>(proj_w, projw, 128, 128);
  swz_kernel<<<256, 256, 0, stream>>>(fc1_w, fc1w, 512, 128);
  swz_kernel<<<256, 256, 0, stream>>>(fc2_w, fc2w, 128, 512);

  attn_kernel<<<4096, 256, 0, stream>>>(x_v, qkvw, qkv_b, rpb_t, attn_ws);
  proj_kernel<<<1024, 256, 0, stream>>>(attn_ws, projw, proj_b, x_v, x_resid);
  mlp_kernel<<<1024, 256, 0, stream>>>(x_resid, fc1w, fc2w, fc1_b, fc2_b, n2w, n2b);
  ln_kernel<<<2048, 256, 0, stream>>>(x_resid, n1w, n1b, (float*)d_out);
}